// Round 1
// baseline (1066.143 us; speedup 1.0000x reference)
//
#include <hip/hip_runtime.h>
#include <math.h>

// Problem constants
#define BB 2
#define LL 2048
#define KK 2048
#define DD 512
#define HH 8
#define HD_ 64
#define RR 8
#define WWIN 8
#define NE (LL * WWIN)   // 16384 edges per batch

__device__ __forceinline__ float gelu_f(float x) {
    // exact erf GELU (torch nn.GELU default / jax approximate=False)
    return 0.5f * x * (1.0f + erff(x * 0.70710678118654752f));
}
__device__ __forceinline__ float softplus_f(float x) {
    return (x > 20.0f) ? x : log1pf(expf(x));
}

// ---------------------------------------------------------------------------
// Generic f32 GEMM: C[M,N] = A[M,Kd] @ W[Kd,N] (+ bias). 64x64 tile, 4x4/thr.
// Requires M%64==0, N%64==0, Kd%16==0.
// ---------------------------------------------------------------------------
__global__ __launch_bounds__(256) void gemm_f32(
    const float* __restrict__ A, const float* __restrict__ W,
    const float* __restrict__ bias, float* __restrict__ C,
    int M, int N, int Kd) {
    __shared__ float As[16][68];
    __shared__ float Bs[16][68];
    const int tid = threadIdx.x;
    const int m0 = blockIdx.x * 64, n0 = blockIdx.y * 64;
    const int tx = tid & 15, ty = tid >> 4;
    const int row_a = tid >> 2, kq_a = (tid & 3) << 2;
    const int kw = tid >> 4, nq = (tid & 15) << 2;
    float acc[4][4] = {};
    for (int k0 = 0; k0 < Kd; k0 += 16) {
        float4 av = *(const float4*)&A[(size_t)(m0 + row_a) * Kd + k0 + kq_a];
        As[kq_a + 0][row_a] = av.x;
        As[kq_a + 1][row_a] = av.y;
        As[kq_a + 2][row_a] = av.z;
        As[kq_a + 3][row_a] = av.w;
        *(float4*)&Bs[kw][nq] = *(const float4*)&W[(size_t)(k0 + kw) * N + n0 + nq];
        __syncthreads();
#pragma unroll
        for (int k = 0; k < 16; ++k) {
            float4 a4 = *(const float4*)&As[k][ty << 2];
            float4 b4 = *(const float4*)&Bs[k][tx << 2];
            acc[0][0] = fmaf(a4.x, b4.x, acc[0][0]);
            acc[0][1] = fmaf(a4.x, b4.y, acc[0][1]);
            acc[0][2] = fmaf(a4.x, b4.z, acc[0][2]);
            acc[0][3] = fmaf(a4.x, b4.w, acc[0][3]);
            acc[1][0] = fmaf(a4.y, b4.x, acc[1][0]);
            acc[1][1] = fmaf(a4.y, b4.y, acc[1][1]);
            acc[1][2] = fmaf(a4.y, b4.z, acc[1][2]);
            acc[1][3] = fmaf(a4.y, b4.w, acc[1][3]);
            acc[2][0] = fmaf(a4.z, b4.x, acc[2][0]);
            acc[2][1] = fmaf(a4.z, b4.y, acc[2][1]);
            acc[2][2] = fmaf(a4.z, b4.z, acc[2][2]);
            acc[2][3] = fmaf(a4.z, b4.w, acc[2][3]);
            acc[3][0] = fmaf(a4.w, b4.x, acc[3][0]);
            acc[3][1] = fmaf(a4.w, b4.y, acc[3][1]);
            acc[3][2] = fmaf(a4.w, b4.z, acc[3][2]);
            acc[3][3] = fmaf(a4.w, b4.w, acc[3][3]);
        }
        __syncthreads();
    }
    float4 bv = make_float4(0.f, 0.f, 0.f, 0.f);
    if (bias) bv = *(const float4*)&bias[n0 + (tx << 2)];
#pragma unroll
    for (int q = 0; q < 4; ++q) {
        float4 o;
        o.x = acc[q][0] + bv.x;
        o.y = acc[q][1] + bv.y;
        o.z = acc[q][2] + bv.z;
        o.w = acc[q][3] + bv.w;
        *(float4*)&C[(size_t)(m0 + (ty << 2) + q) * N + n0 + (tx << 2)] = o;
    }
}

// ---------------------------------------------------------------------------
// Pack the three 16-col first-layer weights into [512,64] (cols 0-15 Ws1,
// 16-31 Wa1, 32-47 Wl1, 48-63 zero) for target (rows 0..511) and context
// (rows 512..1023) halves.
// ---------------------------------------------------------------------------
__global__ void prep_wcat(const float* __restrict__ Ws1, const float* __restrict__ Wa1,
                          const float* __restrict__ Wl1,
                          float* __restrict__ Wct, float* __restrict__ Wcc) {
    int idx = blockIdx.x * 256 + threadIdx.x;
    if (idx >= 512 * 64) return;
    int k = idx >> 6, c = idx & 63;
    float vt = 0.f, vc = 0.f;
    if (c < 16)      { vt = Ws1[k * 16 + c];        vc = Ws1[(512 + k) * 16 + c]; }
    else if (c < 32) { vt = Wa1[k * 16 + (c - 16)]; vc = Wa1[(512 + k) * 16 + (c - 16)]; }
    else if (c < 48) { vt = Wl1[k * 16 + (c - 32)]; vc = Wl1[(512 + k) * 16 + (c - 32)]; }
    Wct[idx] = vt;
    Wcc[idx] = vc;
}

// ---------------------------------------------------------------------------
// Fused scores + top-8: one block per (b,i). Scores over all K in LDS, then
// 8 argmax extractions (tie-break: lower index, matching jax.lax.top_k).
// ---------------------------------------------------------------------------
__global__ __launch_bounds__(256) void scores_topk(
    const float* __restrict__ t64, const float* __restrict__ c64,
    const float* __restrict__ bs1, const float* __restrict__ Ws2,
    const float* __restrict__ bs2, int* __restrict__ edge_j) {
    __shared__ float sc[KK];
    __shared__ float rs[256];
    __shared__ int ri[256];
    const int tid = threadIdx.x;
    const int b = blockIdx.x >> 11;
    const int i = blockIdx.x & (LL - 1);
    float tsb[16], w2[16];
    const float* tr = &t64[(size_t)(b * LL + i) * 64];
#pragma unroll
    for (int k = 0; k < 16; ++k) { tsb[k] = tr[k] + bs1[k]; w2[k] = Ws2[k]; }
    const float b2 = bs2[0];
    for (int j = tid; j < KK; j += 256) {
        const float4* cr4 = (const float4*)&c64[(size_t)(b * KK + j) * 64];
        float creg[16];
        float4 c0 = cr4[0], c1 = cr4[1], c2 = cr4[2], c3 = cr4[3];
        creg[0] = c0.x; creg[1] = c0.y; creg[2] = c0.z; creg[3] = c0.w;
        creg[4] = c1.x; creg[5] = c1.y; creg[6] = c1.z; creg[7] = c1.w;
        creg[8] = c2.x; creg[9] = c2.y; creg[10] = c2.z; creg[11] = c2.w;
        creg[12] = c3.x; creg[13] = c3.y; creg[14] = c3.z; creg[15] = c3.w;
        float s = b2;
#pragma unroll
        for (int k = 0; k < 16; ++k)
            s = fmaf(gelu_f(tsb[k] + creg[k]), w2[k], s);
        sc[j] = s;
    }
    __syncthreads();
    for (int w = 0; w < WWIN; ++w) {
        float bs_ = -INFINITY;
        int bi_ = KK;
        for (int j = tid; j < KK; j += 256) {
            float s = sc[j];
            if (s > bs_) { bs_ = s; bi_ = j; }   // ascending scan keeps lowest idx on ties
        }
        rs[tid] = bs_;
        ri[tid] = bi_;
        __syncthreads();
        for (int off = 128; off > 0; off >>= 1) {
            if (tid < off) {
                float so = rs[tid + off];
                int io = ri[tid + off];
                if (so > rs[tid] || (so == rs[tid] && io < ri[tid])) { rs[tid] = so; ri[tid] = io; }
            }
            __syncthreads();
        }
        if (tid == 0) {
            int bj = ri[0];
            edge_j[(size_t)(b * LL + i) * WWIN + w] = bj;
            sc[bj] = -INFINITY;
        }
        __syncthreads();
    }
}

// ---------------------------------------------------------------------------
// Per-edge params: h16 (Lambda hidden) and alpha. One thread per edge.
// ---------------------------------------------------------------------------
__global__ __launch_bounds__(256) void edge_params(
    const float* __restrict__ t64, const float* __restrict__ c64,
    const int* __restrict__ edge_j,
    const float* __restrict__ bl1, const float* __restrict__ ba1,
    const float* __restrict__ Wa2, const float* __restrict__ ba2,
    float* __restrict__ h16, float* __restrict__ alpha) {
    int idx = blockIdx.x * 256 + threadIdx.x;
    if (idx >= BB * NE) return;
    int b = idx >> 14;                 // / NE (16384)
    int i = (idx & (NE - 1)) >> 3;     // / WWIN
    int j = edge_j[idx];
    const float* tr = &t64[(size_t)(b * LL + i) * 64];
    const float* cr = &c64[(size_t)(b * KK + j) * 64];
    float s = ba2[0];
#pragma unroll
    for (int k = 0; k < 16; ++k) {
        h16[(size_t)idx * 16 + k] = gelu_f(tr[32 + k] + cr[32 + k] + bl1[k]);
        s = fmaf(gelu_f(tr[16 + k] + cr[16 + k] + ba1[k]), Wa2[k], s);
    }
    alpha[idx] = softplus_f(s);
}

// ---------------------------------------------------------------------------
// Fused T=2 consensus iterations. Block = (b, h, 4 consecutive i). One wave
// per (b,h,i), lane = hd dim. Lam expanded on the fly from h16 x Wl2 head
// slice (LDS), normalized fragments lamn[w][r] kept in registers and reused
// across both iterations (t-independent). u updated in place (own row only).
// ---------------------------------------------------------------------------
__global__ __launch_bounds__(256) void iterate_k(
    float* __restrict__ u, const float* __restrict__ v,
    const int* __restrict__ edge_j, const float* __restrict__ alpha,
    const float* __restrict__ h16,
    const float* __restrict__ Wl2, const float* __restrict__ bl2,
    const float* __restrict__ step_sizes) {
    __shared__ float wl2s[16][512];
    __shared__ float bl2s[512];
    __shared__ float h16s[32][16];
    __shared__ float alphs[32];
    __shared__ int ejs[32];
    const int tid = threadIdx.x;
    const int h = blockIdx.y, b = blockIdx.z;
    const int i0 = blockIdx.x << 2;
    const int e0 = b * NE + (i0 << 3);   // 32 contiguous edges for this block

    for (int s = tid; s < 16 * 128; s += 256) {
        int k = s >> 7, c4 = (s & 127) << 2;
        *(float4*)&wl2s[k][c4] = *(const float4*)&Wl2[(size_t)k * (HH * RR * HD_) + h * 512 + c4];
    }
    if (tid < 128) *(float4*)&bl2s[tid << 2] = *(const float4*)&bl2[h * 512 + (tid << 2)];
    for (int s = tid; s < 32 * 16; s += 256) h16s[s >> 4][s & 15] = h16[(size_t)e0 * 16 + s];
    if (tid < 32) { ejs[tid] = edge_j[e0 + tid]; alphs[tid] = alpha[e0 + tid]; }
    __syncthreads();

    const int wv = tid >> 6, lane = tid & 63;
    const int i = i0 + wv;
    const size_t urow = ((size_t)(b * LL + i)) * DD + h * HD_ + lane;
    float u_d = u[urow];
    const float st0 = softplus_f(step_sizes[i]);
    const float st1 = softplus_f(step_sizes[LL + i]);

    // Phase 1: normalized Lam fragments, t-independent
    float lamn[8][8];
#pragma unroll
    for (int r = 0; r < 8; ++r) {
        float wreg[16];
#pragma unroll
        for (int k = 0; k < 16; ++k) wreg[k] = wl2s[k][(r << 6) + lane];
        const float blv = bl2s[(r << 6) + lane];
#pragma unroll
        for (int w = 0; w < 8; ++w) {
            const int le = (wv << 3) + w;
            float lam = blv;
#pragma unroll
            for (int k = 0; k < 16; ++k) lam = fmaf(h16s[le][k], wreg[k], lam);
            float ss = lam * lam;
#pragma unroll
            for (int m = 1; m < 64; m <<= 1) ss += __shfl_xor(ss, m);
            float inv = 1.0f / fmaxf(sqrtf(ss), 1e-12f);
            lamn[w][r] = lam * inv;
        }
    }

    // Phase 2: preload per-edge v rows, rotary cos/sin, alpha
    const int k31 = lane & 31;
    const float invf = 1.0f / powf(10000.0f, (float)k31 * (1.0f / 32.0f));
    float vw[8], cw[8], sw[8], aw[8];
#pragma unroll
    for (int w = 0; w < 8; ++w) {
        const int le = (wv << 3) + w;
        const int j = ejs[le];
        aw[w] = alphs[le];
        vw[w] = v[((size_t)(b * KK + j)) * DD + h * HD_ + lane];
        float ang = (float)(i - j) * invf;
        sincosf(ang, &sw[w], &cw[w]);
    }

#pragma unroll
    for (int t = 0; t < 2; ++t) {
        float up = __shfl_xor(u_d, 32);
        float rotb = (lane < 32) ? -up : up;     // rotate_half
        float resid = 0.0f;
#pragma unroll
        for (int w = 0; w < 8; ++w) {
            float ui = u_d * cw[w] + rotb * sw[w];
            float diff = ui - vw[w];
            resid = fmaf(aw[w], diff, resid);
#pragma unroll
            for (int r = 0; r < 8; ++r) {
                float dt = lamn[w][r] * diff;
#pragma unroll
                for (int m = 1; m < 64; m <<= 1) dt += __shfl_xor(dt, m);
                resid = fmaf(dt, lamn[w][r], resid);
            }
        }
        u_d = fmaf((t == 0) ? -st0 : -st1, resid, u_d);
    }
    u[urow] = u_d;
}

// ---------------------------------------------------------------------------
extern "C" void kernel_launch(void* const* d_in, const int* in_sizes, int n_in,
                              void* d_out, int out_size, void* d_ws, size_t ws_size,
                              hipStream_t stream) {
    (void)in_sizes; (void)n_in; (void)out_size; (void)ws_size;
    const float* target     = (const float*)d_in[0];
    const float* context    = (const float*)d_in[1];
    const float* Wt         = (const float*)d_in[2];
    const float* bt         = (const float*)d_in[3];
    const float* Wc         = (const float*)d_in[4];
    const float* bc         = (const float*)d_in[5];
    const float* Ws1        = (const float*)d_in[6];
    const float* bs1        = (const float*)d_in[7];
    const float* Ws2        = (const float*)d_in[8];
    const float* bs2        = (const float*)d_in[9];
    const float* Wa1        = (const float*)d_in[10];
    const float* ba1        = (const float*)d_in[11];
    const float* Wa2        = (const float*)d_in[12];
    const float* ba2        = (const float*)d_in[13];
    const float* Wl1        = (const float*)d_in[14];
    const float* bl1        = (const float*)d_in[15];
    const float* Wl2        = (const float*)d_in[16];
    const float* bl2        = (const float*)d_in[17];
    const float* step_sizes = (const float*)d_in[18];
    const float* Wo         = (const float*)d_in[19];
    const float* bo         = (const float*)d_in[20];
    float* out = (float*)d_out;

    float* ws = (float*)d_ws;
    float* u    = ws;                    // 4096*512 = 2097152
    float* v    = ws + 2097152;          // 2097152
    float* t64  = ws + 4194304;          // 4096*64 = 262144
    float* c64  = ws + 4456448;          // 262144
    float* h16  = ws + 4718592;          // 32768*16 = 524288
    float* alph = ws + 5242880;          // 32768
    int*   ej   = (int*)(ws + 5275648);  // 32768
    float* wct  = ws + 5308416;          // 512*64 = 32768
    float* wcc  = ws + 5341184;          // 32768

    prep_wcat<<<dim3((512 * 64 + 255) / 256), dim3(256), 0, stream>>>(Ws1, Wa1, Wl1, wct, wcc);

    gemm_f32<<<dim3(64, 8), dim3(256), 0, stream>>>(target,  Wt,  bt,      u,   4096, 512, 512);
    gemm_f32<<<dim3(64, 8), dim3(256), 0, stream>>>(context, Wc,  bc,      v,   4096, 512, 512);
    gemm_f32<<<dim3(64, 1), dim3(256), 0, stream>>>(target,  wct, nullptr, t64, 4096, 64,  512);
    gemm_f32<<<dim3(64, 1), dim3(256), 0, stream>>>(context, wcc, nullptr, c64, 4096, 64,  512);

    scores_topk<<<dim3(BB * LL), dim3(256), 0, stream>>>(t64, c64, bs1, Ws2, bs2, ej);

    edge_params<<<dim3(BB * NE / 256), dim3(256), 0, stream>>>(t64, c64, ej, bl1, ba1, Wa2, ba2, h16, alph);

    iterate_k<<<dim3(LL / 4, HH, BB), dim3(256), 0, stream>>>(u, v, ej, alph, h16, Wl2, bl2, step_sizes);

    gemm_f32<<<dim3(64, 8), dim3(256), 0, stream>>>(u, Wo, bo, out, 4096, 512, 512);
}

// Round 2
// 506.314 us; speedup vs baseline: 2.1057x; 2.1057x over previous
//
#include <hip/hip_runtime.h>
#include <math.h>

// Problem constants
#define BB 2
#define LL 2048
#define KK 2048
#define DD 512
#define HH 8
#define HD_ 64
#define RR 8
#define WWIN 8
#define NE (LL * WWIN)   // 16384 edges per batch

__device__ __forceinline__ float gelu_f(float x) {
    // exact erf GELU (torch nn.GELU default / jax approximate=False)
    return 0.5f * x * (1.0f + erff(x * 0.70710678118654752f));
}
__device__ __forceinline__ float softplus_f(float x) {
    return (x > 20.0f) ? x : log1pf(expf(x));
}

// ---------------------------------------------------------------------------
// Generic f32 GEMM: C[M,N] = A[M,Kd] @ W[Kd,N] (+ bias). 64x64 tile, 4x4/thr.
// Requires M%64==0, N%64==0, Kd%16==0.
// ---------------------------------------------------------------------------
__global__ __launch_bounds__(256) void gemm_f32(
    const float* __restrict__ A, const float* __restrict__ W,
    const float* __restrict__ bias, float* __restrict__ C,
    int M, int N, int Kd) {
    __shared__ float As[16][68];
    __shared__ float Bs[16][68];
    const int tid = threadIdx.x;
    const int m0 = blockIdx.x * 64, n0 = blockIdx.y * 64;
    const int tx = tid & 15, ty = tid >> 4;
    const int row_a = tid >> 2, kq_a = (tid & 3) << 2;
    const int kw = tid >> 4, nq = (tid & 15) << 2;
    float acc[4][4] = {};
    for (int k0 = 0; k0 < Kd; k0 += 16) {
        float4 av = *(const float4*)&A[(size_t)(m0 + row_a) * Kd + k0 + kq_a];
        As[kq_a + 0][row_a] = av.x;
        As[kq_a + 1][row_a] = av.y;
        As[kq_a + 2][row_a] = av.z;
        As[kq_a + 3][row_a] = av.w;
        *(float4*)&Bs[kw][nq] = *(const float4*)&W[(size_t)(k0 + kw) * N + n0 + nq];
        __syncthreads();
#pragma unroll
        for (int k = 0; k < 16; ++k) {
            float4 a4 = *(const float4*)&As[k][ty << 2];
            float4 b4 = *(const float4*)&Bs[k][tx << 2];
            acc[0][0] = fmaf(a4.x, b4.x, acc[0][0]);
            acc[0][1] = fmaf(a4.x, b4.y, acc[0][1]);
            acc[0][2] = fmaf(a4.x, b4.z, acc[0][2]);
            acc[0][3] = fmaf(a4.x, b4.w, acc[0][3]);
            acc[1][0] = fmaf(a4.y, b4.x, acc[1][0]);
            acc[1][1] = fmaf(a4.y, b4.y, acc[1][1]);
            acc[1][2] = fmaf(a4.y, b4.z, acc[1][2]);
            acc[1][3] = fmaf(a4.y, b4.w, acc[1][3]);
            acc[2][0] = fmaf(a4.z, b4.x, acc[2][0]);
            acc[2][1] = fmaf(a4.z, b4.y, acc[2][1]);
            acc[2][2] = fmaf(a4.z, b4.z, acc[2][2]);
            acc[2][3] = fmaf(a4.z, b4.w, acc[2][3]);
            acc[3][0] = fmaf(a4.w, b4.x, acc[3][0]);
            acc[3][1] = fmaf(a4.w, b4.y, acc[3][1]);
            acc[3][2] = fmaf(a4.w, b4.z, acc[3][2]);
            acc[3][3] = fmaf(a4.w, b4.w, acc[3][3]);
        }
        __syncthreads();
    }
    float4 bv = make_float4(0.f, 0.f, 0.f, 0.f);
    if (bias) bv = *(const float4*)&bias[n0 + (tx << 2)];
#pragma unroll
    for (int q = 0; q < 4; ++q) {
        float4 o;
        o.x = acc[q][0] + bv.x;
        o.y = acc[q][1] + bv.y;
        o.z = acc[q][2] + bv.z;
        o.w = acc[q][3] + bv.w;
        *(float4*)&C[(size_t)(m0 + (ty << 2) + q) * N + n0 + (tx << 2)] = o;
    }
}

// ---------------------------------------------------------------------------
// Pack the three 16-col first-layer weights into [512,64] (cols 0-15 Ws1,
// 16-31 Wa1, 32-47 Wl1, 48-63 zero) for target (rows 0..511) and context
// (rows 512..1023) halves.
// ---------------------------------------------------------------------------
__global__ void prep_wcat(const float* __restrict__ Ws1, const float* __restrict__ Wa1,
                          const float* __restrict__ Wl1,
                          float* __restrict__ Wct, float* __restrict__ Wcc) {
    int idx = blockIdx.x * 256 + threadIdx.x;
    if (idx >= 512 * 64) return;
    int k = idx >> 6, c = idx & 63;
    float vt = 0.f, vc = 0.f;
    if (c < 16)      { vt = Ws1[k * 16 + c];        vc = Ws1[(512 + k) * 16 + c]; }
    else if (c < 32) { vt = Wa1[k * 16 + (c - 16)]; vc = Wa1[(512 + k) * 16 + (c - 16)]; }
    else if (c < 48) { vt = Wl1[k * 16 + (c - 32)]; vc = Wl1[(512 + k) * 16 + (c - 32)]; }
    Wct[idx] = vt;
    Wcc[idx] = vc;
}

// ---------------------------------------------------------------------------
// Fused scores + top-8: one block per (b,i). Scores over all K in LDS, then
// 8 argmax extractions (tie-break: lower index, matching jax.lax.top_k).
// ---------------------------------------------------------------------------
__global__ __launch_bounds__(256) void scores_topk(
    const float* __restrict__ t64, const float* __restrict__ c64,
    const float* __restrict__ bs1, const float* __restrict__ Ws2,
    const float* __restrict__ bs2, int* __restrict__ edge_j) {
    __shared__ float sc[KK];
    __shared__ float rs[256];
    __shared__ int ri[256];
    const int tid = threadIdx.x;
    const int b = blockIdx.x >> 11;
    const int i = blockIdx.x & (LL - 1);
    float tsb[16], w2[16];
    const float* tr = &t64[(size_t)(b * LL + i) * 64];
#pragma unroll
    for (int k = 0; k < 16; ++k) { tsb[k] = tr[k] + bs1[k]; w2[k] = Ws2[k]; }
    const float b2 = bs2[0];
    for (int j = tid; j < KK; j += 256) {
        const float4* cr4 = (const float4*)&c64[(size_t)(b * KK + j) * 64];
        float creg[16];
        float4 c0 = cr4[0], c1 = cr4[1], c2 = cr4[2], c3 = cr4[3];
        creg[0] = c0.x; creg[1] = c0.y; creg[2] = c0.z; creg[3] = c0.w;
        creg[4] = c1.x; creg[5] = c1.y; creg[6] = c1.z; creg[7] = c1.w;
        creg[8] = c2.x; creg[9] = c2.y; creg[10] = c2.z; creg[11] = c2.w;
        creg[12] = c3.x; creg[13] = c3.y; creg[14] = c3.z; creg[15] = c3.w;
        float s = b2;
#pragma unroll
        for (int k = 0; k < 16; ++k)
            s = fmaf(gelu_f(tsb[k] + creg[k]), w2[k], s);
        sc[j] = s;
    }
    __syncthreads();
    for (int w = 0; w < WWIN; ++w) {
        float bs_ = -INFINITY;
        int bi_ = KK;
        for (int j = tid; j < KK; j += 256) {
            float s = sc[j];
            if (s > bs_) { bs_ = s; bi_ = j; }   // ascending scan keeps lowest idx on ties
        }
        rs[tid] = bs_;
        ri[tid] = bi_;
        __syncthreads();
        for (int off = 128; off > 0; off >>= 1) {
            if (tid < off) {
                float so = rs[tid + off];
                int io = ri[tid + off];
                if (so > rs[tid] || (so == rs[tid] && io < ri[tid])) { rs[tid] = so; ri[tid] = io; }
            }
            __syncthreads();
        }
        if (tid == 0) {
            int bj = ri[0];
            edge_j[(size_t)(b * LL + i) * WWIN + w] = bj;
            sc[bj] = -INFINITY;
        }
        __syncthreads();
    }
}

// ---------------------------------------------------------------------------
// Per-edge params: h16 (Lambda hidden) and alpha. One thread per edge.
// ---------------------------------------------------------------------------
__global__ __launch_bounds__(256) void edge_params(
    const float* __restrict__ t64, const float* __restrict__ c64,
    const int* __restrict__ edge_j,
    const float* __restrict__ bl1, const float* __restrict__ ba1,
    const float* __restrict__ Wa2, const float* __restrict__ ba2,
    float* __restrict__ h16, float* __restrict__ alpha) {
    int idx = blockIdx.x * 256 + threadIdx.x;
    if (idx >= BB * NE) return;
    int b = idx >> 14;                 // / NE (16384)
    int i = (idx & (NE - 1)) >> 3;     // / WWIN
    int j = edge_j[idx];
    const float* tr = &t64[(size_t)(b * LL + i) * 64];
    const float* cr = &c64[(size_t)(b * KK + j) * 64];
    float s = ba2[0];
#pragma unroll
    for (int k = 0; k < 16; ++k) {
        h16[(size_t)idx * 16 + k] = gelu_f(tr[32 + k] + cr[32 + k] + bl1[k]);
        s = fmaf(gelu_f(tr[16 + k] + cr[16 + k] + ba1[k]), Wa2[k], s);
    }
    alpha[idx] = softplus_f(s);
}

// ---------------------------------------------------------------------------
// Fused T=2 consensus iterations. Block = (b, h, 4 consecutive i). One wave
// per (b,h,i), lane = hd dim.
//
// All 64-wide reductions use a reduce-scatter butterfly: lane d holds 64
// partials q[idx]; 6 select+exchange steps (63 shuffles total, vs 64*6=384
// for naive per-value reduction) leave the full sum for idx==lane on lane
// idx. Distribute-back uses __shfl(x, const) -> v_readlane broadcasts (no
// DS traffic).
// ---------------------------------------------------------------------------
__global__ __launch_bounds__(256) void iterate_k(
    float* __restrict__ u, const float* __restrict__ v,
    const int* __restrict__ edge_j, const float* __restrict__ alpha,
    const float* __restrict__ h16,
    const float* __restrict__ Wl2, const float* __restrict__ bl2,
    const float* __restrict__ step_sizes) {
    __shared__ float wl2s[16][512];
    __shared__ float bl2s[512];
    __shared__ float h16s[32][16];
    __shared__ float alphs[32];
    __shared__ int ejs[32];
    const int tid = threadIdx.x;
    const int h = blockIdx.y, b = blockIdx.z;
    const int i0 = blockIdx.x << 2;
    const int e0 = b * NE + (i0 << 3);   // 32 contiguous edges for this block

    for (int s = tid; s < 16 * 128; s += 256) {
        int k = s >> 7, c4 = (s & 127) << 2;
        *(float4*)&wl2s[k][c4] = *(const float4*)&Wl2[(size_t)k * (HH * RR * HD_) + h * 512 + c4];
    }
    if (tid < 128) *(float4*)&bl2s[tid << 2] = *(const float4*)&bl2[h * 512 + (tid << 2)];
    for (int s = tid; s < 32 * 16; s += 256) h16s[s >> 4][s & 15] = h16[(size_t)e0 * 16 + s];
    if (tid < 32) { ejs[tid] = edge_j[e0 + tid]; alphs[tid] = alpha[e0 + tid]; }
    __syncthreads();

    const int wv = tid >> 6, lane = tid & 63;
    const int i = i0 + wv;
    const size_t urow = ((size_t)(b * LL + i)) * DD + h * HD_ + lane;
    float u_d = u[urow];
    const float st0 = softplus_f(step_sizes[i]);
    const float st1 = softplus_f(step_sizes[LL + i]);

    const bool up32 = (lane & 32) != 0;
    const bool up16 = (lane & 16) != 0;
    const bool up8  = (lane & 8) != 0;
    const bool up4  = (lane & 4) != 0;
    const bool up2  = (lane & 2) != 0;
    const bool up1  = (lane & 1) != 0;

    // Phase 1: expand un-normalized Lam fragments (lane = d)
    float lamn[8][8];
#pragma unroll
    for (int r = 0; r < 8; ++r) {
        float wreg[16];
#pragma unroll
        for (int k = 0; k < 16; ++k) wreg[k] = wl2s[k][(r << 6) + lane];
        const float blv = bl2s[(r << 6) + lane];
#pragma unroll
        for (int w = 0; w < 8; ++w) {
            const int le = (wv << 3) + w;
            float lam = blv;
#pragma unroll
            for (int k = 0; k < 16; ++k) lam = fmaf(h16s[le][k], wreg[k], lam);
            lamn[w][r] = lam;
        }
    }

    // Normalize: reduce-scatter of squared sums, one sqrt per lane, then
    // readlane-broadcast the 64 inverse norms back.
    {
        float q[64];
#pragma unroll
        for (int w = 0; w < 8; ++w)
#pragma unroll
            for (int r = 0; r < 8; ++r) {
                float x = lamn[w][r];
                q[(w << 3) + r] = x * x;
            }
#pragma unroll
        for (int j = 0; j < 32; ++j) {
            float lo = q[j], hi = q[j + 32];
            float recv = __shfl_xor(up32 ? lo : hi, 32);
            q[j] = (up32 ? hi : lo) + recv;
        }
#pragma unroll
        for (int j = 0; j < 16; ++j) {
            float lo = q[j], hi = q[j + 16];
            float recv = __shfl_xor(up16 ? lo : hi, 16);
            q[j] = (up16 ? hi : lo) + recv;
        }
#pragma unroll
        for (int j = 0; j < 8; ++j) {
            float lo = q[j], hi = q[j + 8];
            float recv = __shfl_xor(up8 ? lo : hi, 8);
            q[j] = (up8 ? hi : lo) + recv;
        }
#pragma unroll
        for (int j = 0; j < 4; ++j) {
            float lo = q[j], hi = q[j + 4];
            float recv = __shfl_xor(up4 ? lo : hi, 4);
            q[j] = (up4 ? hi : lo) + recv;
        }
#pragma unroll
        for (int j = 0; j < 2; ++j) {
            float lo = q[j], hi = q[j + 2];
            float recv = __shfl_xor(up2 ? lo : hi, 2);
            q[j] = (up2 ? hi : lo) + recv;
        }
        {
            float lo = q[0], hi = q[1];
            float recv = __shfl_xor(up1 ? lo : hi, 1);
            q[0] = (up1 ? hi : lo) + recv;
        }
        // q[0] = sum_d lam[idx==lane]^2
        float my_inv = 1.0f / fmaxf(sqrtf(q[0]), 1e-12f);
#pragma unroll
        for (int w = 0; w < 8; ++w)
#pragma unroll
            for (int r = 0; r < 8; ++r)
                lamn[w][r] *= __shfl(my_inv, (w << 3) + r);
    }

    // Phase 2: preload per-edge v rows, rotary cos/sin, alpha
    const int k31 = lane & 31;
    const float invf = 1.0f / powf(10000.0f, (float)k31 * (1.0f / 32.0f));
    float vw[8], cw[8], sw[8], aw[8];
#pragma unroll
    for (int w = 0; w < 8; ++w) {
        const int le = (wv << 3) + w;
        const int j = ejs[le];
        aw[w] = alphs[le];
        vw[w] = v[((size_t)(b * KK + j)) * DD + h * HD_ + lane];
        float ang = (float)(i - j) * invf;
        sincosf(ang, &sw[w], &cw[w]);
    }

#pragma unroll
    for (int t = 0; t < 2; ++t) {
        float upv = __shfl_xor(u_d, 32);
        float rotb = (lane < 32) ? -upv : upv;   // rotate_half
        float resid = 0.0f;
        float q[64];
#pragma unroll
        for (int w = 0; w < 8; ++w) {
            float ui = u_d * cw[w] + rotb * sw[w];
            float diff = ui - vw[w];
            resid = fmaf(aw[w], diff, resid);
#pragma unroll
            for (int r = 0; r < 8; ++r) q[(w << 3) + r] = lamn[w][r] * diff;
        }
        // reduce-scatter: dt[idx] lands on lane idx
#pragma unroll
        for (int j = 0; j < 32; ++j) {
            float lo = q[j], hi = q[j + 32];
            float recv = __shfl_xor(up32 ? lo : hi, 32);
            q[j] = (up32 ? hi : lo) + recv;
        }
#pragma unroll
        for (int j = 0; j < 16; ++j) {
            float lo = q[j], hi = q[j + 16];
            float recv = __shfl_xor(up16 ? lo : hi, 16);
            q[j] = (up16 ? hi : lo) + recv;
        }
#pragma unroll
        for (int j = 0; j < 8; ++j) {
            float lo = q[j], hi = q[j + 8];
            float recv = __shfl_xor(up8 ? lo : hi, 8);
            q[j] = (up8 ? hi : lo) + recv;
        }
#pragma unroll
        for (int j = 0; j < 4; ++j) {
            float lo = q[j], hi = q[j + 4];
            float recv = __shfl_xor(up4 ? lo : hi, 4);
            q[j] = (up4 ? hi : lo) + recv;
        }
#pragma unroll
        for (int j = 0; j < 2; ++j) {
            float lo = q[j], hi = q[j + 2];
            float recv = __shfl_xor(up2 ? lo : hi, 2);
            q[j] = (up2 ? hi : lo) + recv;
        }
        {
            float lo = q[0], hi = q[1];
            float recv = __shfl_xor(up1 ? lo : hi, 1);
            q[0] = (up1 ? hi : lo) + recv;
        }
        float dt = q[0];   // dt for (w=lane>>3, r=lane&7)
        // distribute-back: resid[d] += sum_idx dt[idx] * lamn[idx] (readlane)
#pragma unroll
        for (int w = 0; w < 8; ++w)
#pragma unroll
            for (int r = 0; r < 8; ++r)
                resid = fmaf(__shfl(dt, (w << 3) + r), lamn[w][r], resid);
        u_d = fmaf((t == 0) ? -st0 : -st1, resid, u_d);
    }
    u[urow] = u_d;
}

// ---------------------------------------------------------------------------
extern "C" void kernel_launch(void* const* d_in, const int* in_sizes, int n_in,
                              void* d_out, int out_size, void* d_ws, size_t ws_size,
                              hipStream_t stream) {
    (void)in_sizes; (void)n_in; (void)out_size; (void)ws_size;
    const float* target     = (const float*)d_in[0];
    const float* context    = (const float*)d_in[1];
    const float* Wt         = (const float*)d_in[2];
    const float* bt         = (const float*)d_in[3];
    const float* Wc         = (const float*)d_in[4];
    const float* bc         = (const float*)d_in[5];
    const float* Ws1        = (const float*)d_in[6];
    const float* bs1        = (const float*)d_in[7];
    const float* Ws2        = (const float*)d_in[8];
    const float* bs2        = (const float*)d_in[9];
    const float* Wa1        = (const float*)d_in[10];
    const float* ba1        = (const float*)d_in[11];
    const float* Wa2        = (const float*)d_in[12];
    const float* ba2        = (const float*)d_in[13];
    const float* Wl1        = (const float*)d_in[14];
    const float* bl1        = (const float*)d_in[15];
    const float* Wl2        = (const float*)d_in[16];
    const float* bl2        = (const float*)d_in[17];
    const float* step_sizes = (const float*)d_in[18];
    const float* Wo         = (const float*)d_in[19];
    const float* bo         = (const float*)d_in[20];
    float* out = (float*)d_out;

    float* ws = (float*)d_ws;
    float* u    = ws;                    // 4096*512 = 2097152
    float* v    = ws + 2097152;          // 2097152
    float* t64  = ws + 4194304;          // 4096*64 = 262144
    float* c64  = ws + 4456448;          // 262144
    float* h16  = ws + 4718592;          // 32768*16 = 524288
    float* alph = ws + 5242880;          // 32768
    int*   ej   = (int*)(ws + 5275648);  // 32768
    float* wct  = ws + 5308416;          // 512*64 = 32768
    float* wcc  = ws + 5341184;          // 32768

    prep_wcat<<<dim3((512 * 64 + 255) / 256), dim3(256), 0, stream>>>(Ws1, Wa1, Wl1, wct, wcc);

    gemm_f32<<<dim3(64, 8), dim3(256), 0, stream>>>(target,  Wt,  bt,      u,   4096, 512, 512);
    gemm_f32<<<dim3(64, 8), dim3(256), 0, stream>>>(context, Wc,  bc,      v,   4096, 512, 512);
    gemm_f32<<<dim3(64, 1), dim3(256), 0, stream>>>(target,  wct, nullptr, t64, 4096, 64,  512);
    gemm_f32<<<dim3(64, 1), dim3(256), 0, stream>>>(context, wcc, nullptr, c64, 4096, 64,  512);

    scores_topk<<<dim3(BB * LL), dim3(256), 0, stream>>>(t64, c64, bs1, Ws2, bs2, ej);

    edge_params<<<dim3(BB * NE / 256), dim3(256), 0, stream>>>(t64, c64, ej, bl1, ba1, Wa2, ba2, h16, alph);

    iterate_k<<<dim3(LL / 4, HH, BB), dim3(256), 0, stream>>>(u, v, ej, alph, h16, Wl2, bl2, step_sizes);

    gemm_f32<<<dim3(64, 8), dim3(256), 0, stream>>>(u, Wo, bo, out, 4096, 512, 512);
}

// Round 3
// 388.813 us; speedup vs baseline: 2.7420x; 1.3022x over previous
//
#include <hip/hip_runtime.h>
#include <math.h>

// Problem constants
#define BB 2
#define LL 2048
#define KK 2048
#define DD 512
#define HH 8
#define HD_ 64
#define RR 8
#define WWIN 8
#define NE (LL * WWIN)   // 16384 edges per batch

typedef __attribute__((ext_vector_type(8))) short bf16x8s;
typedef __attribute__((ext_vector_type(4))) float f32x4;

__device__ __forceinline__ float gelu_f(float x) {
    return 0.5f * x * (1.0f + erff(x * 0.70710678118654752f));
}
__device__ __forceinline__ float softplus_f(float x) {
    return (x > 20.0f) ? x : log1pf(expf(x));
}
__device__ __forceinline__ short f2bf(float f) {
    unsigned int x = __float_as_uint(f);
    x += 0x7FFFu + ((x >> 16) & 1u);   // RTNE
    return (short)(x >> 16);
}

// ---------------------------------------------------------------------------
// bf16-MFMA GEMM: C[M,N] = A[M,Kd]@W[Kd,N] (+bias), f32 in/out, bf16 compute.
// Tile 128x64, BK=32, 4 waves (2M x 2N), wave tile 64x32, frags 4x2 of 16x16.
// Requires M%128==0, N%64==0, Kd%32==0.
// ---------------------------------------------------------------------------
__global__ __launch_bounds__(256) void gemm_bf16(
    const float* __restrict__ A, const float* __restrict__ W,
    const float* __restrict__ bias, float* __restrict__ C,
    int M, int N, int Kd) {
    __shared__ short As[128][40];   // [m][k] bf16, row stride 80B (pad)
    __shared__ short Bs[64][40];    // [n][k] bf16 (transposed), row stride 80B
    const int tid = threadIdx.x;
    const int m0 = blockIdx.x * 128, n0 = blockIdx.y * 64;
    const int wv = tid >> 6, lane = tid & 63;
    const int wm = (wv & 1) << 6, wn = (wv >> 1) << 5;
    const int l15 = lane & 15, lg = lane >> 4;

    f32x4 acc[4][2] = {};
    union S8 { bf16x8s v; short s[8]; };

    const int arow = tid >> 1, akh = (tid & 1) << 4;
    const int bk = tid >> 3, bnb = (tid & 7) << 3;

    for (int k0 = 0; k0 < Kd; k0 += 32) {
        // stage A: 128x32 f32 -> bf16
        {
            const float* ap = &A[(size_t)(m0 + arow) * Kd + k0 + akh];
            float4 f0 = *(const float4*)(ap + 0);
            float4 f1 = *(const float4*)(ap + 4);
            float4 f2 = *(const float4*)(ap + 8);
            float4 f3 = *(const float4*)(ap + 12);
            S8 s0, s1;
            s0.s[0] = f2bf(f0.x); s0.s[1] = f2bf(f0.y); s0.s[2] = f2bf(f0.z); s0.s[3] = f2bf(f0.w);
            s0.s[4] = f2bf(f1.x); s0.s[5] = f2bf(f1.y); s0.s[6] = f2bf(f1.z); s0.s[7] = f2bf(f1.w);
            s1.s[0] = f2bf(f2.x); s1.s[1] = f2bf(f2.y); s1.s[2] = f2bf(f2.z); s1.s[3] = f2bf(f2.w);
            s1.s[4] = f2bf(f3.x); s1.s[5] = f2bf(f3.y); s1.s[6] = f2bf(f3.z); s1.s[7] = f2bf(f3.w);
            *(bf16x8s*)&As[arow][akh] = s0.v;
            *(bf16x8s*)&As[arow][akh + 8] = s1.v;
        }
        // stage B (transpose): W[k0+bk][n0+bnb..+7] -> Bs[n][k]
        {
            const float* wp = &W[(size_t)(k0 + bk) * N + n0 + bnb];
            float4 w0 = *(const float4*)(wp + 0);
            float4 w1 = *(const float4*)(wp + 4);
            Bs[bnb + 0][bk] = f2bf(w0.x);
            Bs[bnb + 1][bk] = f2bf(w0.y);
            Bs[bnb + 2][bk] = f2bf(w0.z);
            Bs[bnb + 3][bk] = f2bf(w0.w);
            Bs[bnb + 4][bk] = f2bf(w1.x);
            Bs[bnb + 5][bk] = f2bf(w1.y);
            Bs[bnb + 6][bk] = f2bf(w1.z);
            Bs[bnb + 7][bk] = f2bf(w1.w);
        }
        __syncthreads();
        bf16x8s af[4], bf[2];
#pragma unroll
        for (int mf = 0; mf < 4; ++mf)
            af[mf] = *(const bf16x8s*)&As[wm + (mf << 4) + l15][lg << 3];
#pragma unroll
        for (int nf = 0; nf < 2; ++nf)
            bf[nf] = *(const bf16x8s*)&Bs[wn + (nf << 4) + l15][lg << 3];
#pragma unroll
        for (int mf = 0; mf < 4; ++mf)
#pragma unroll
            for (int nf = 0; nf < 2; ++nf)
                acc[mf][nf] = __builtin_amdgcn_mfma_f32_16x16x32_bf16(af[mf], bf[nf], acc[mf][nf], 0, 0, 0);
        __syncthreads();
    }
    // epilogue: C/D layout col=lane&15, row=(lane>>4)*4+j
    float bv[2] = {0.f, 0.f};
    if (bias) {
        bv[0] = bias[n0 + wn + l15];
        bv[1] = bias[n0 + wn + 16 + l15];
    }
#pragma unroll
    for (int mf = 0; mf < 4; ++mf)
#pragma unroll
        for (int nf = 0; nf < 2; ++nf)
#pragma unroll
            for (int j = 0; j < 4; ++j) {
                int crow = m0 + wm + (mf << 4) + (lg << 2) + j;
                int ccol = n0 + wn + (nf << 4) + l15;
                C[(size_t)crow * N + ccol] = acc[mf][nf][j] + bv[nf];
            }
}

// ---------------------------------------------------------------------------
// Generic f32 GEMM (kept for t64/c64: exact scores -> stable top-k).
// ---------------------------------------------------------------------------
__global__ __launch_bounds__(256) void gemm_f32(
    const float* __restrict__ A, const float* __restrict__ W,
    const float* __restrict__ bias, float* __restrict__ C,
    int M, int N, int Kd) {
    __shared__ float As[16][68];
    __shared__ float Bs[16][68];
    const int tid = threadIdx.x;
    const int m0 = blockIdx.x * 64, n0 = blockIdx.y * 64;
    const int tx = tid & 15, ty = tid >> 4;
    const int row_a = tid >> 2, kq_a = (tid & 3) << 2;
    const int kw = tid >> 4, nq = (tid & 15) << 2;
    float acc[4][4] = {};
    for (int k0 = 0; k0 < Kd; k0 += 16) {
        float4 av = *(const float4*)&A[(size_t)(m0 + row_a) * Kd + k0 + kq_a];
        As[kq_a + 0][row_a] = av.x;
        As[kq_a + 1][row_a] = av.y;
        As[kq_a + 2][row_a] = av.z;
        As[kq_a + 3][row_a] = av.w;
        *(float4*)&Bs[kw][nq] = *(const float4*)&W[(size_t)(k0 + kw) * N + n0 + nq];
        __syncthreads();
#pragma unroll
        for (int k = 0; k < 16; ++k) {
            float4 a4 = *(const float4*)&As[k][ty << 2];
            float4 b4 = *(const float4*)&Bs[k][tx << 2];
            acc[0][0] = fmaf(a4.x, b4.x, acc[0][0]);
            acc[0][1] = fmaf(a4.x, b4.y, acc[0][1]);
            acc[0][2] = fmaf(a4.x, b4.z, acc[0][2]);
            acc[0][3] = fmaf(a4.x, b4.w, acc[0][3]);
            acc[1][0] = fmaf(a4.y, b4.x, acc[1][0]);
            acc[1][1] = fmaf(a4.y, b4.y, acc[1][1]);
            acc[1][2] = fmaf(a4.y, b4.z, acc[1][2]);
            acc[1][3] = fmaf(a4.y, b4.w, acc[1][3]);
            acc[2][0] = fmaf(a4.z, b4.x, acc[2][0]);
            acc[2][1] = fmaf(a4.z, b4.y, acc[2][1]);
            acc[2][2] = fmaf(a4.z, b4.z, acc[2][2]);
            acc[2][3] = fmaf(a4.z, b4.w, acc[2][3]);
            acc[3][0] = fmaf(a4.w, b4.x, acc[3][0]);
            acc[3][1] = fmaf(a4.w, b4.y, acc[3][1]);
            acc[3][2] = fmaf(a4.w, b4.z, acc[3][2]);
            acc[3][3] = fmaf(a4.w, b4.w, acc[3][3]);
        }
        __syncthreads();
    }
    float4 bv = make_float4(0.f, 0.f, 0.f, 0.f);
    if (bias) bv = *(const float4*)&bias[n0 + (tx << 2)];
#pragma unroll
    for (int q = 0; q < 4; ++q) {
        float4 o;
        o.x = acc[q][0] + bv.x;
        o.y = acc[q][1] + bv.y;
        o.z = acc[q][2] + bv.z;
        o.w = acc[q][3] + bv.w;
        *(float4*)&C[(size_t)(m0 + (ty << 2) + q) * N + n0 + (tx << 2)] = o;
    }
}

// ---------------------------------------------------------------------------
__global__ void prep_wcat(const float* __restrict__ Ws1, const float* __restrict__ Wa1,
                          const float* __restrict__ Wl1,
                          float* __restrict__ Wct, float* __restrict__ Wcc) {
    int idx = blockIdx.x * 256 + threadIdx.x;
    if (idx >= 512 * 64) return;
    int k = idx >> 6, c = idx & 63;
    float vt = 0.f, vc = 0.f;
    if (c < 16)      { vt = Ws1[k * 16 + c];        vc = Ws1[(512 + k) * 16 + c]; }
    else if (c < 32) { vt = Wa1[k * 16 + (c - 16)]; vc = Wa1[(512 + k) * 16 + (c - 16)]; }
    else if (c < 48) { vt = Wl1[k * 16 + (c - 32)]; vc = Wl1[(512 + k) * 16 + (c - 32)]; }
    Wct[idx] = vt;
    Wcc[idx] = vc;
}

// ---------------------------------------------------------------------------
// Fused scores + top-8 (tie-break: lowest index, matching jax.lax.top_k).
// ---------------------------------------------------------------------------
__global__ __launch_bounds__(256) void scores_topk(
    const float* __restrict__ t64, const float* __restrict__ c64,
    const float* __restrict__ bs1, const float* __restrict__ Ws2,
    const float* __restrict__ bs2, int* __restrict__ edge_j) {
    __shared__ float sc[KK];
    __shared__ float rs[256];
    __shared__ int ri[256];
    const int tid = threadIdx.x;
    const int b = blockIdx.x >> 11;
    const int i = blockIdx.x & (LL - 1);
    float tsb[16], w2[16];
    const float* tr = &t64[(size_t)(b * LL + i) * 64];
#pragma unroll
    for (int k = 0; k < 16; ++k) { tsb[k] = tr[k] + bs1[k]; w2[k] = Ws2[k]; }
    const float b2 = bs2[0];
    for (int j = tid; j < KK; j += 256) {
        const float4* cr4 = (const float4*)&c64[(size_t)(b * KK + j) * 64];
        float creg[16];
        float4 c0 = cr4[0], c1 = cr4[1], c2 = cr4[2], c3 = cr4[3];
        creg[0] = c0.x; creg[1] = c0.y; creg[2] = c0.z; creg[3] = c0.w;
        creg[4] = c1.x; creg[5] = c1.y; creg[6] = c1.z; creg[7] = c1.w;
        creg[8] = c2.x; creg[9] = c2.y; creg[10] = c2.z; creg[11] = c2.w;
        creg[12] = c3.x; creg[13] = c3.y; creg[14] = c3.z; creg[15] = c3.w;
        float s = b2;
#pragma unroll
        for (int k = 0; k < 16; ++k)
            s = fmaf(gelu_f(tsb[k] + creg[k]), w2[k], s);
        sc[j] = s;
    }
    __syncthreads();
    for (int w = 0; w < WWIN; ++w) {
        float bs_ = -INFINITY;
        int bi_ = KK;
        for (int j = tid; j < KK; j += 256) {
            float s = sc[j];
            if (s > bs_) { bs_ = s; bi_ = j; }
        }
        rs[tid] = bs_;
        ri[tid] = bi_;
        __syncthreads();
        for (int off = 128; off > 0; off >>= 1) {
            if (tid < off) {
                float so = rs[tid + off];
                int io = ri[tid + off];
                if (so > rs[tid] || (so == rs[tid] && io < ri[tid])) { rs[tid] = so; ri[tid] = io; }
            }
            __syncthreads();
        }
        if (tid == 0) {
            int bj = ri[0];
            edge_j[(size_t)(b * LL + i) * WWIN + w] = bj;
            sc[bj] = -INFINITY;
        }
        __syncthreads();
    }
}

// ---------------------------------------------------------------------------
__global__ __launch_bounds__(256) void edge_params(
    const float* __restrict__ t64, const float* __restrict__ c64,
    const int* __restrict__ edge_j,
    const float* __restrict__ bl1, const float* __restrict__ ba1,
    const float* __restrict__ Wa2, const float* __restrict__ ba2,
    float* __restrict__ h16, float* __restrict__ alpha) {
    int idx = blockIdx.x * 256 + threadIdx.x;
    if (idx >= BB * NE) return;
    int b = idx >> 14;
    int i = (idx & (NE - 1)) >> 3;
    int j = edge_j[idx];
    const float* tr = &t64[(size_t)(b * LL + i) * 64];
    const float* cr = &c64[(size_t)(b * KK + j) * 64];
    float s = ba2[0];
#pragma unroll
    for (int k = 0; k < 16; ++k) {
        h16[(size_t)idx * 16 + k] = gelu_f(tr[32 + k] + cr[32 + k] + bl1[k]);
        s = fmaf(gelu_f(tr[16 + k] + cr[16 + k] + ba1[k]), Wa2[k], s);
    }
    alpha[idx] = softplus_f(s);
}

// ---------------------------------------------------------------------------
// Fused T=2 consensus iterations. Block = (b,h,4 i). One wave per (b,h,i),
// lane = hd dim. Changes vs R1:
//  - Wl2/bl2 operands read from GLOBAL (per-head slice = 32KB = L1-resident)
//    instead of LDS; only h16 staged in LDS (broadcast reads).
//  - No normalization broadcast: resid uses raw lam and dt/ss with
//    inv_ss = 1/max(ss,1e-24) applied on lane idx (Lam appears twice).
//  - xor-32 butterfly step fused into q-build (live q regs 64 -> 32).
//  - distribute-back via 1 ds_write + 16 float4 broadcast LDS reads.
// ---------------------------------------------------------------------------
__global__ __launch_bounds__(256, 3) void iterate_k(
    float* __restrict__ u, const float* __restrict__ v,
    const int* __restrict__ edge_j, const float* __restrict__ alpha,
    const float* __restrict__ h16,
    const float* __restrict__ Wl2, const float* __restrict__ bl2,
    const float* __restrict__ step_sizes) {
    __shared__ float h16s[32][16];
    __shared__ float alphs[32];
    __shared__ int ejs[32];
    __shared__ float dts[4][64];
    const int tid = threadIdx.x;
    const int h = blockIdx.y, b = blockIdx.z;
    const int i0 = blockIdx.x << 2;
    const int e0 = b * NE + (i0 << 3);

    for (int s = tid; s < 512; s += 256) h16s[s >> 4][s & 15] = h16[(size_t)e0 * 16 + s];
    if (tid < 32) { ejs[tid] = edge_j[e0 + tid]; alphs[tid] = alpha[e0 + tid]; }
    __syncthreads();

    const int wv = tid >> 6, lane = tid & 63;
    const int i = i0 + wv;
    const size_t urow = ((size_t)(b * LL + i)) * DD + h * HD_ + lane;
    float u_d = u[urow];
    const float st0 = softplus_f(step_sizes[i]);
    const float st1 = softplus_f(step_sizes[LL + i]);

    const bool up32 = (lane & 32) != 0;
    const bool up16 = (lane & 16) != 0;
    const bool up8  = (lane & 8) != 0;
    const bool up4  = (lane & 4) != 0;
    const bool up2  = (lane & 2) != 0;
    const bool up1  = (lane & 1) != 0;

    const float* wl2h = Wl2 + (size_t)h * 512;   // element [k][col]: wl2h[k*4096 + col]
    const float* bl2h = bl2 + h * 512;

    // Phase 1: raw Lam fragments (lane = d), r in two halves of 4 (VGPR cap)
    float lamr[8][8];
#pragma unroll
    for (int half = 0; half < 2; ++half) {
        float wreg[4][16];
        float blv[4];
#pragma unroll
        for (int r4 = 0; r4 < 4; ++r4) {
            const int col = ((half * 4 + r4) << 6) + lane;
            blv[r4] = bl2h[col];
#pragma unroll
            for (int k = 0; k < 16; ++k)
                wreg[r4][k] = wl2h[(size_t)k * 4096 + col];
        }
#pragma unroll
        for (int w = 0; w < 8; ++w) {
            const int le = (wv << 3) + w;
            float hr[16];
#pragma unroll
            for (int kq = 0; kq < 4; ++kq) {
                float4 h4 = *(const float4*)&h16s[le][kq << 2];
                hr[(kq << 2) + 0] = h4.x;
                hr[(kq << 2) + 1] = h4.y;
                hr[(kq << 2) + 2] = h4.z;
                hr[(kq << 2) + 3] = h4.w;
            }
#pragma unroll
            for (int r4 = 0; r4 < 4; ++r4) {
                float lam = blv[r4];
#pragma unroll
                for (int k = 0; k < 16; ++k) lam = fmaf(hr[k], wreg[r4][k], lam);
                lamr[w][(half << 2) + r4] = lam;
            }
        }
    }

    // ss reduce-scatter (xor-32 fused into build); inv_ss lands on lane idx
    float inv_ss;
    {
        float q[32];
#pragma unroll
        for (int wp = 0; wp < 4; ++wp)
#pragma unroll
            for (int r = 0; r < 8; ++r) {
                float plo = lamr[wp][r] * lamr[wp][r];
                float phi = lamr[wp + 4][r] * lamr[wp + 4][r];
                float recv = __shfl_xor(up32 ? plo : phi, 32);
                q[(wp << 3) + r] = (up32 ? phi : plo) + recv;
            }
#pragma unroll
        for (int j = 0; j < 16; ++j) {
            float lo = q[j], hi = q[j + 16];
            float recv = __shfl_xor(up16 ? lo : hi, 16);
            q[j] = (up16 ? hi : lo) + recv;
        }
#pragma unroll
        for (int j = 0; j < 8; ++j) {
            float lo = q[j], hi = q[j + 8];
            float recv = __shfl_xor(up8 ? lo : hi, 8);
            q[j] = (up8 ? hi : lo) + recv;
        }
#pragma unroll
        for (int j = 0; j < 4; ++j) {
            float lo = q[j], hi = q[j + 4];
            float recv = __shfl_xor(up4 ? lo : hi, 4);
            q[j] = (up4 ? hi : lo) + recv;
        }
#pragma unroll
        for (int j = 0; j < 2; ++j) {
            float lo = q[j], hi = q[j + 2];
            float recv = __shfl_xor(up2 ? lo : hi, 2);
            q[j] = (up2 ? hi : lo) + recv;
        }
        {
            float lo = q[0], hi = q[1];
            float recv = __shfl_xor(up1 ? lo : hi, 1);
            q[0] = (up1 ? hi : lo) + recv;
        }
        inv_ss = 1.0f / fmaxf(q[0], 1e-24f);
    }

    // Phase 2: per-edge v rows, rotary cos/sin, alpha
    const int k31 = lane & 31;
    const float invf = exp2f((float)k31 * (-13.287712379549449f / 32.0f));  // 10000^(-k31/32)
    float vw[8], cw[8], sw[8], aw[8];
#pragma unroll
    for (int w = 0; w < 8; ++w) {
        const int le = (wv << 3) + w;
        const int j = ejs[le];
        aw[w] = alphs[le];
        vw[w] = v[((size_t)(b * KK + j)) * DD + h * HD_ + lane];
        float ang = (float)(i - j) * invf;
        sincosf(ang, &sw[w], &cw[w]);
    }

#pragma unroll
    for (int t = 0; t < 2; ++t) {
        float upv = __shfl_xor(u_d, 32);
        float rotb = (lane < 32) ? -upv : upv;   // rotate_half
        float resid = 0.0f;
        float q[32];
#pragma unroll
        for (int wp = 0; wp < 4; ++wp) {
            float dlo = fmaf(u_d, cw[wp], rotb * sw[wp]) - vw[wp];
            float dhi = fmaf(u_d, cw[wp + 4], rotb * sw[wp + 4]) - vw[wp + 4];
            resid = fmaf(aw[wp], dlo, resid);
            resid = fmaf(aw[wp + 4], dhi, resid);
#pragma unroll
            for (int r = 0; r < 8; ++r) {
                float plo = lamr[wp][r] * dlo;
                float phi = lamr[wp + 4][r] * dhi;
                float recv = __shfl_xor(up32 ? plo : phi, 32);
                q[(wp << 3) + r] = (up32 ? phi : plo) + recv;
            }
        }
#pragma unroll
        for (int j = 0; j < 16; ++j) {
            float lo = q[j], hi = q[j + 16];
            float recv = __shfl_xor(up16 ? lo : hi, 16);
            q[j] = (up16 ? hi : lo) + recv;
        }
#pragma unroll
        for (int j = 0; j < 8; ++j) {
            float lo = q[j], hi = q[j + 8];
            float recv = __shfl_xor(up8 ? lo : hi, 8);
            q[j] = (up8 ? hi : lo) + recv;
        }
#pragma unroll
        for (int j = 0; j < 4; ++j) {
            float lo = q[j], hi = q[j + 4];
            float recv = __shfl_xor(up4 ? lo : hi, 4);
            q[j] = (up4 ? hi : lo) + recv;
        }
#pragma unroll
        for (int j = 0; j < 2; ++j) {
            float lo = q[j], hi = q[j + 2];
            float recv = __shfl_xor(up2 ? lo : hi, 2);
            q[j] = (up2 ? hi : lo) + recv;
        }
        {
            float lo = q[0], hi = q[1];
            float recv = __shfl_xor(up1 ? lo : hi, 1);
            q[0] = (up1 ? hi : lo) + recv;
        }
        // dt/ss for (w=lane>>3, r=lane&7) sits on lane; share via LDS
        dts[wv][lane] = q[0] * inv_ss;   // same-wave write->read, lgkmcnt-ordered
#pragma unroll
        for (int w = 0; w < 8; ++w) {
            float4 da = *(const float4*)&dts[wv][(w << 3)];
            float4 db = *(const float4*)&dts[wv][(w << 3) + 4];
            resid = fmaf(da.x, lamr[w][0], resid);
            resid = fmaf(da.y, lamr[w][1], resid);
            resid = fmaf(da.z, lamr[w][2], resid);
            resid = fmaf(da.w, lamr[w][3], resid);
            resid = fmaf(db.x, lamr[w][4], resid);
            resid = fmaf(db.y, lamr[w][5], resid);
            resid = fmaf(db.z, lamr[w][6], resid);
            resid = fmaf(db.w, lamr[w][7], resid);
        }
        u_d = fmaf((t == 0) ? -st0 : -st1, resid, u_d);
    }
    u[urow] = u_d;
}

// ---------------------------------------------------------------------------
extern "C" void kernel_launch(void* const* d_in, const int* in_sizes, int n_in,
                              void* d_out, int out_size, void* d_ws, size_t ws_size,
                              hipStream_t stream) {
    (void)in_sizes; (void)n_in; (void)out_size; (void)ws_size;
    const float* target     = (const float*)d_in[0];
    const float* context    = (const float*)d_in[1];
    const float* Wt         = (const float*)d_in[2];
    const float* bt         = (const float*)d_in[3];
    const float* Wc         = (const float*)d_in[4];
    const float* bc         = (const float*)d_in[5];
    const float* Ws1        = (const float*)d_in[6];
    const float* bs1        = (const float*)d_in[7];
    const float* Ws2        = (const float*)d_in[8];
    const float* bs2        = (const float*)d_in[9];
    const float* Wa1        = (const float*)d_in[10];
    const float* ba1        = (const float*)d_in[11];
    const float* Wa2        = (const float*)d_in[12];
    const float* ba2        = (const float*)d_in[13];
    const float* Wl1        = (const float*)d_in[14];
    const float* bl1        = (const float*)d_in[15];
    const float* Wl2        = (const float*)d_in[16];
    const float* bl2        = (const float*)d_in[17];
    const float* step_sizes = (const float*)d_in[18];
    const float* Wo         = (const float*)d_in[19];
    const float* bo         = (const float*)d_in[20];
    float* out = (float*)d_out;

    float* ws = (float*)d_ws;
    float* u    = ws;                    // 4096*512
    float* v    = ws + 2097152;
    float* t64  = ws + 4194304;          // 4096*64
    float* c64  = ws + 4456448;
    float* h16  = ws + 4718592;          // 32768*16
    float* alph = ws + 5242880;
    int*   ej   = (int*)(ws + 5275648);
    float* wct  = ws + 5308416;
    float* wcc  = ws + 5341184;

    prep_wcat<<<dim3((512 * 64 + 255) / 256), dim3(256), 0, stream>>>(Ws1, Wa1, Wl1, wct, wcc);

    gemm_bf16<<<dim3(32, 8), dim3(256), 0, stream>>>(target,  Wt, bt, u, 4096, 512, 512);
    gemm_bf16<<<dim3(32, 8), dim3(256), 0, stream>>>(context, Wc, bc, v, 4096, 512, 512);
    gemm_f32<<<dim3(64, 1), dim3(256), 0, stream>>>(target,  wct, nullptr, t64, 4096, 64, 512);
    gemm_f32<<<dim3(64, 1), dim3(256), 0, stream>>>(context, wcc, nullptr, c64, 4096, 64, 512);

    scores_topk<<<dim3(BB * LL), dim3(256), 0, stream>>>(t64, c64, bs1, Ws2, bs2, ej);

    edge_params<<<dim3(BB * NE / 256), dim3(256), 0, stream>>>(t64, c64, ej, bl1, ba1, Wa2, ba2, h16, alph);

    iterate_k<<<dim3(LL / 4, HH, BB), dim3(256), 0, stream>>>(u, v, ej, alph, h16, Wl2, bl2, step_sizes);

    gemm_bf16<<<dim3(32, 8), dim3(256), 0, stream>>>(u, Wo, bo, out, 4096, 512, 512);
}

// Round 4
// 388.697 us; speedup vs baseline: 2.7429x; 1.0003x over previous
//
#include <hip/hip_runtime.h>
#include <math.h>

// Problem constants
#define BB 2
#define LL 2048
#define KK 2048
#define DD 512
#define HH 8
#define HD_ 64
#define RR 8
#define WWIN 8
#define NE (LL * WWIN)   // 16384 edges per batch

typedef __attribute__((ext_vector_type(8))) short bf16x8s;
typedef __attribute__((ext_vector_type(4))) float f32x4;

__device__ __forceinline__ float gelu_f(float x) {
    return 0.5f * x * (1.0f + erff(x * 0.70710678118654752f));
}
__device__ __forceinline__ float softplus_f(float x) {
    return (x > 20.0f) ? x : log1pf(expf(x));
}
__device__ __forceinline__ short f2bf(float f) {
    unsigned int x = __float_as_uint(f);
    x += 0x7FFFu + ((x >> 16) & 1u);   // RTNE
    return (short)(x >> 16);
}

// ---------------------------------------------------------------------------
// bf16-MFMA GEMM: C[M,N] = A[M,Kd]@W[Kd,N] (+bias), f32 in/out, bf16 compute.
// Tile 128x64, BK=32, 4 waves (2M x 2N), wave tile 64x32, frags 4x2 of 16x16.
// Requires M%128==0, N%64==0, Kd%32==0.
// ---------------------------------------------------------------------------
__global__ __launch_bounds__(256) void gemm_bf16(
    const float* __restrict__ A, const float* __restrict__ W,
    const float* __restrict__ bias, float* __restrict__ C,
    int M, int N, int Kd) {
    __shared__ short As[128][40];   // [m][k] bf16, row stride 80B (pad)
    __shared__ short Bs[64][40];    // [n][k] bf16 (transposed), row stride 80B
    const int tid = threadIdx.x;
    const int m0 = blockIdx.x * 128, n0 = blockIdx.y * 64;
    const int wv = tid >> 6, lane = tid & 63;
    const int wm = (wv & 1) << 6, wn = (wv >> 1) << 5;
    const int l15 = lane & 15, lg = lane >> 4;

    f32x4 acc[4][2] = {};
    union S8 { bf16x8s v; short s[8]; };

    const int arow = tid >> 1, akh = (tid & 1) << 4;
    const int bk = tid >> 3, bnb = (tid & 7) << 3;

    for (int k0 = 0; k0 < Kd; k0 += 32) {
        // stage A: 128x32 f32 -> bf16
        {
            const float* ap = &A[(size_t)(m0 + arow) * Kd + k0 + akh];
            float4 f0 = *(const float4*)(ap + 0);
            float4 f1 = *(const float4*)(ap + 4);
            float4 f2 = *(const float4*)(ap + 8);
            float4 f3 = *(const float4*)(ap + 12);
            S8 s0, s1;
            s0.s[0] = f2bf(f0.x); s0.s[1] = f2bf(f0.y); s0.s[2] = f2bf(f0.z); s0.s[3] = f2bf(f0.w);
            s0.s[4] = f2bf(f1.x); s0.s[5] = f2bf(f1.y); s0.s[6] = f2bf(f1.z); s0.s[7] = f2bf(f1.w);
            s1.s[0] = f2bf(f2.x); s1.s[1] = f2bf(f2.y); s1.s[2] = f2bf(f2.z); s1.s[3] = f2bf(f2.w);
            s1.s[4] = f2bf(f3.x); s1.s[5] = f2bf(f3.y); s1.s[6] = f2bf(f3.z); s1.s[7] = f2bf(f3.w);
            *(bf16x8s*)&As[arow][akh] = s0.v;
            *(bf16x8s*)&As[arow][akh + 8] = s1.v;
        }
        // stage B (transpose): W[k0+bk][n0+bnb..+7] -> Bs[n][k]
        {
            const float* wp = &W[(size_t)(k0 + bk) * N + n0 + bnb];
            float4 w0 = *(const float4*)(wp + 0);
            float4 w1 = *(const float4*)(wp + 4);
            Bs[bnb + 0][bk] = f2bf(w0.x);
            Bs[bnb + 1][bk] = f2bf(w0.y);
            Bs[bnb + 2][bk] = f2bf(w0.z);
            Bs[bnb + 3][bk] = f2bf(w0.w);
            Bs[bnb + 4][bk] = f2bf(w1.x);
            Bs[bnb + 5][bk] = f2bf(w1.y);
            Bs[bnb + 6][bk] = f2bf(w1.z);
            Bs[bnb + 7][bk] = f2bf(w1.w);
        }
        __syncthreads();
        bf16x8s af[4], bf[2];
#pragma unroll
        for (int mf = 0; mf < 4; ++mf)
            af[mf] = *(const bf16x8s*)&As[wm + (mf << 4) + l15][lg << 3];
#pragma unroll
        for (int nf = 0; nf < 2; ++nf)
            bf[nf] = *(const bf16x8s*)&Bs[wn + (nf << 4) + l15][lg << 3];
#pragma unroll
        for (int mf = 0; mf < 4; ++mf)
#pragma unroll
            for (int nf = 0; nf < 2; ++nf)
                acc[mf][nf] = __builtin_amdgcn_mfma_f32_16x16x32_bf16(af[mf], bf[nf], acc[mf][nf], 0, 0, 0);
        __syncthreads();
    }
    // epilogue: C/D layout col=lane&15, row=(lane>>4)*4+j
    float bv[2] = {0.f, 0.f};
    if (bias) {
        bv[0] = bias[n0 + wn + l15];
        bv[1] = bias[n0 + wn + 16 + l15];
    }
#pragma unroll
    for (int mf = 0; mf < 4; ++mf)
#pragma unroll
        for (int nf = 0; nf < 2; ++nf)
#pragma unroll
            for (int j = 0; j < 4; ++j) {
                int crow = m0 + wm + (mf << 4) + (lg << 2) + j;
                int ccol = n0 + wn + (nf << 4) + l15;
                C[(size_t)crow * N + ccol] = acc[mf][nf][j] + bv[nf];
            }
}

// ---------------------------------------------------------------------------
// Generic f32 GEMM (kept for t64/c64: exact scores -> stable top-k).
// ---------------------------------------------------------------------------
__global__ __launch_bounds__(256) void gemm_f32(
    const float* __restrict__ A, const float* __restrict__ W,
    const float* __restrict__ bias, float* __restrict__ C,
    int M, int N, int Kd) {
    __shared__ float As[16][68];
    __shared__ float Bs[16][68];
    const int tid = threadIdx.x;
    const int m0 = blockIdx.x * 64, n0 = blockIdx.y * 64;
    const int tx = tid & 15, ty = tid >> 4;
    const int row_a = tid >> 2, kq_a = (tid & 3) << 2;
    const int kw = tid >> 4, nq = (tid & 15) << 2;
    float acc[4][4] = {};
    for (int k0 = 0; k0 < Kd; k0 += 16) {
        float4 av = *(const float4*)&A[(size_t)(m0 + row_a) * Kd + k0 + kq_a];
        As[kq_a + 0][row_a] = av.x;
        As[kq_a + 1][row_a] = av.y;
        As[kq_a + 2][row_a] = av.z;
        As[kq_a + 3][row_a] = av.w;
        *(float4*)&Bs[kw][nq] = *(const float4*)&W[(size_t)(k0 + kw) * N + n0 + nq];
        __syncthreads();
#pragma unroll
        for (int k = 0; k < 16; ++k) {
            float4 a4 = *(const float4*)&As[k][ty << 2];
            float4 b4 = *(const float4*)&Bs[k][tx << 2];
            acc[0][0] = fmaf(a4.x, b4.x, acc[0][0]);
            acc[0][1] = fmaf(a4.x, b4.y, acc[0][1]);
            acc[0][2] = fmaf(a4.x, b4.z, acc[0][2]);
            acc[0][3] = fmaf(a4.x, b4.w, acc[0][3]);
            acc[1][0] = fmaf(a4.y, b4.x, acc[1][0]);
            acc[1][1] = fmaf(a4.y, b4.y, acc[1][1]);
            acc[1][2] = fmaf(a4.y, b4.z, acc[1][2]);
            acc[1][3] = fmaf(a4.y, b4.w, acc[1][3]);
            acc[2][0] = fmaf(a4.z, b4.x, acc[2][0]);
            acc[2][1] = fmaf(a4.z, b4.y, acc[2][1]);
            acc[2][2] = fmaf(a4.z, b4.z, acc[2][2]);
            acc[2][3] = fmaf(a4.z, b4.w, acc[2][3]);
            acc[3][0] = fmaf(a4.w, b4.x, acc[3][0]);
            acc[3][1] = fmaf(a4.w, b4.y, acc[3][1]);
            acc[3][2] = fmaf(a4.w, b4.z, acc[3][2]);
            acc[3][3] = fmaf(a4.w, b4.w, acc[3][3]);
        }
        __syncthreads();
    }
    float4 bv = make_float4(0.f, 0.f, 0.f, 0.f);
    if (bias) bv = *(const float4*)&bias[n0 + (tx << 2)];
#pragma unroll
    for (int q = 0; q < 4; ++q) {
        float4 o;
        o.x = acc[q][0] + bv.x;
        o.y = acc[q][1] + bv.y;
        o.z = acc[q][2] + bv.z;
        o.w = acc[q][3] + bv.w;
        *(float4*)&C[(size_t)(m0 + (ty << 2) + q) * N + n0 + (tx << 2)] = o;
    }
}

// ---------------------------------------------------------------------------
__global__ void prep_wcat(const float* __restrict__ Ws1, const float* __restrict__ Wa1,
                          const float* __restrict__ Wl1,
                          float* __restrict__ Wct, float* __restrict__ Wcc) {
    int idx = blockIdx.x * 256 + threadIdx.x;
    if (idx >= 512 * 64) return;
    int k = idx >> 6, c = idx & 63;
    float vt = 0.f, vc = 0.f;
    if (c < 16)      { vt = Ws1[k * 16 + c];        vc = Ws1[(512 + k) * 16 + c]; }
    else if (c < 32) { vt = Wa1[k * 16 + (c - 16)]; vc = Wa1[(512 + k) * 16 + (c - 16)]; }
    else if (c < 48) { vt = Wl1[k * 16 + (c - 32)]; vc = Wl1[(512 + k) * 16 + (c - 32)]; }
    Wct[idx] = vt;
    Wcc[idx] = vc;
}

// ---------------------------------------------------------------------------
// Fused scores + top-8 (tie-break: lowest index, matching jax.lax.top_k).
// ---------------------------------------------------------------------------
__global__ __launch_bounds__(256) void scores_topk(
    const float* __restrict__ t64, const float* __restrict__ c64,
    const float* __restrict__ bs1, const float* __restrict__ Ws2,
    const float* __restrict__ bs2, int* __restrict__ edge_j) {
    __shared__ float sc[KK];
    __shared__ float rs[256];
    __shared__ int ri[256];
    const int tid = threadIdx.x;
    const int b = blockIdx.x >> 11;
    const int i = blockIdx.x & (LL - 1);
    float tsb[16], w2[16];
    const float* tr = &t64[(size_t)(b * LL + i) * 64];
#pragma unroll
    for (int k = 0; k < 16; ++k) { tsb[k] = tr[k] + bs1[k]; w2[k] = Ws2[k]; }
    const float b2 = bs2[0];
    for (int j = tid; j < KK; j += 256) {
        const float4* cr4 = (const float4*)&c64[(size_t)(b * KK + j) * 64];
        float creg[16];
        float4 c0 = cr4[0], c1 = cr4[1], c2 = cr4[2], c3 = cr4[3];
        creg[0] = c0.x; creg[1] = c0.y; creg[2] = c0.z; creg[3] = c0.w;
        creg[4] = c1.x; creg[5] = c1.y; creg[6] = c1.z; creg[7] = c1.w;
        creg[8] = c2.x; creg[9] = c2.y; creg[10] = c2.z; creg[11] = c2.w;
        creg[12] = c3.x; creg[13] = c3.y; creg[14] = c3.z; creg[15] = c3.w;
        float s = b2;
#pragma unroll
        for (int k = 0; k < 16; ++k)
            s = fmaf(gelu_f(tsb[k] + creg[k]), w2[k], s);
        sc[j] = s;
    }
    __syncthreads();
    for (int w = 0; w < WWIN; ++w) {
        float bs_ = -INFINITY;
        int bi_ = KK;
        for (int j = tid; j < KK; j += 256) {
            float s = sc[j];
            if (s > bs_) { bs_ = s; bi_ = j; }
        }
        rs[tid] = bs_;
        ri[tid] = bi_;
        __syncthreads();
        for (int off = 128; off > 0; off >>= 1) {
            if (tid < off) {
                float so = rs[tid + off];
                int io = ri[tid + off];
                if (so > rs[tid] || (so == rs[tid] && io < ri[tid])) { rs[tid] = so; ri[tid] = io; }
            }
            __syncthreads();
        }
        if (tid == 0) {
            int bj = ri[0];
            edge_j[(size_t)(b * LL + i) * WWIN + w] = bj;
            sc[bj] = -INFINITY;
        }
        __syncthreads();
    }
}

// ---------------------------------------------------------------------------
__global__ __launch_bounds__(256) void edge_params(
    const float* __restrict__ t64, const float* __restrict__ c64,
    const int* __restrict__ edge_j,
    const float* __restrict__ bl1, const float* __restrict__ ba1,
    const float* __restrict__ Wa2, const float* __restrict__ ba2,
    float* __restrict__ h16, float* __restrict__ alpha) {
    int idx = blockIdx.x * 256 + threadIdx.x;
    if (idx >= BB * NE) return;
    int b = idx >> 14;
    int i = (idx & (NE - 1)) >> 3;
    int j = edge_j[idx];
    const float* tr = &t64[(size_t)(b * LL + i) * 64];
    const float* cr = &c64[(size_t)(b * KK + j) * 64];
    float s = ba2[0];
#pragma unroll
    for (int k = 0; k < 16; ++k) {
        h16[(size_t)idx * 16 + k] = gelu_f(tr[32 + k] + cr[32 + k] + bl1[k]);
        s = fmaf(gelu_f(tr[16 + k] + cr[16 + k] + ba1[k]), Wa2[k], s);
    }
    alpha[idx] = softplus_f(s);
}

// ---------------------------------------------------------------------------
// Fused T=2 consensus iterations. Block = (b,h,4 i). One wave per (b,h,i),
// lane = hd dim. Changes vs R1:
//  - Wl2/bl2 operands read from GLOBAL (per-head slice = 32KB = L1-resident)
//    instead of LDS; only h16 staged in LDS (broadcast reads).
//  - No normalization broadcast: resid uses raw lam and dt/ss with
//    inv_ss = 1/max(ss,1e-24) applied on lane idx (Lam appears twice).
//  - xor-32 butterfly step fused into q-build (live q regs 64 -> 32).
//  - distribute-back via 1 ds_write + 16 float4 broadcast LDS reads.
// ---------------------------------------------------------------------------
__global__ __launch_bounds__(256, 3) void iterate_k(
    float* __restrict__ u, const float* __restrict__ v,
    const int* __restrict__ edge_j, const float* __restrict__ alpha,
    const float* __restrict__ h16,
    const float* __restrict__ Wl2, const float* __restrict__ bl2,
    const float* __restrict__ step_sizes) {
    __shared__ float h16s[32][16];
    __shared__ float alphs[32];
    __shared__ int ejs[32];
    __shared__ float dts[4][64];
    const int tid = threadIdx.x;
    const int h = blockIdx.y, b = blockIdx.z;
    const int i0 = blockIdx.x << 2;
    const int e0 = b * NE + (i0 << 3);

    for (int s = tid; s < 512; s += 256) h16s[s >> 4][s & 15] = h16[(size_t)e0 * 16 + s];
    if (tid < 32) { ejs[tid] = edge_j[e0 + tid]; alphs[tid] = alpha[e0 + tid]; }
    __syncthreads();

    const int wv = tid >> 6, lane = tid & 63;
    const int i = i0 + wv;
    const size_t urow = ((size_t)(b * LL + i)) * DD + h * HD_ + lane;
    float u_d = u[urow];
    const float st0 = softplus_f(step_sizes[i]);
    const float st1 = softplus_f(step_sizes[LL + i]);

    const bool up32 = (lane & 32) != 0;
    const bool up16 = (lane & 16) != 0;
    const bool up8  = (lane & 8) != 0;
    const bool up4  = (lane & 4) != 0;
    const bool up2  = (lane & 2) != 0;
    const bool up1  = (lane & 1) != 0;

    const float* wl2h = Wl2 + (size_t)h * 512;   // element [k][col]: wl2h[k*4096 + col]
    const float* bl2h = bl2 + h * 512;

    // Phase 1: raw Lam fragments (lane = d), r in two halves of 4 (VGPR cap)
    float lamr[8][8];
#pragma unroll
    for (int half = 0; half < 2; ++half) {
        float wreg[4][16];
        float blv[4];
#pragma unroll
        for (int r4 = 0; r4 < 4; ++r4) {
            const int col = ((half * 4 + r4) << 6) + lane;
            blv[r4] = bl2h[col];
#pragma unroll
            for (int k = 0; k < 16; ++k)
                wreg[r4][k] = wl2h[(size_t)k * 4096 + col];
        }
#pragma unroll
        for (int w = 0; w < 8; ++w) {
            const int le = (wv << 3) + w;
            float hr[16];
#pragma unroll
            for (int kq = 0; kq < 4; ++kq) {
                float4 h4 = *(const float4*)&h16s[le][kq << 2];
                hr[(kq << 2) + 0] = h4.x;
                hr[(kq << 2) + 1] = h4.y;
                hr[(kq << 2) + 2] = h4.z;
                hr[(kq << 2) + 3] = h4.w;
            }
#pragma unroll
            for (int r4 = 0; r4 < 4; ++r4) {
                float lam = blv[r4];
#pragma unroll
                for (int k = 0; k < 16; ++k) lam = fmaf(hr[k], wreg[r4][k], lam);
                lamr[w][(half << 2) + r4] = lam;
            }
        }
    }

    // ss reduce-scatter (xor-32 fused into build); inv_ss lands on lane idx
    float inv_ss;
    {
        float q[32];
#pragma unroll
        for (int wp = 0; wp < 4; ++wp)
#pragma unroll
            for (int r = 0; r < 8; ++r) {
                float plo = lamr[wp][r] * lamr[wp][r];
                float phi = lamr[wp + 4][r] * lamr[wp + 4][r];
                float recv = __shfl_xor(up32 ? plo : phi, 32);
                q[(wp << 3) + r] = (up32 ? phi : plo) + recv;
            }
#pragma unroll
        for (int j = 0; j < 16; ++j) {
            float lo = q[j], hi = q[j + 16];
            float recv = __shfl_xor(up16 ? lo : hi, 16);
            q[j] = (up16 ? hi : lo) + recv;
        }
#pragma unroll
        for (int j = 0; j < 8; ++j) {
            float lo = q[j], hi = q[j + 8];
            float recv = __shfl_xor(up8 ? lo : hi, 8);
            q[j] = (up8 ? hi : lo) + recv;
        }
#pragma unroll
        for (int j = 0; j < 4; ++j) {
            float lo = q[j], hi = q[j + 4];
            float recv = __shfl_xor(up4 ? lo : hi, 4);
            q[j] = (up4 ? hi : lo) + recv;
        }
#pragma unroll
        for (int j = 0; j < 2; ++j) {
            float lo = q[j], hi = q[j + 2];
            float recv = __shfl_xor(up2 ? lo : hi, 2);
            q[j] = (up2 ? hi : lo) + recv;
        }
        {
            float lo = q[0], hi = q[1];
            float recv = __shfl_xor(up1 ? lo : hi, 1);
            q[0] = (up1 ? hi : lo) + recv;
        }
        inv_ss = 1.0f / fmaxf(q[0], 1e-24f);
    }

    // Phase 2: per-edge v rows, rotary cos/sin, alpha
    const int k31 = lane & 31;
    const float invf = exp2f((float)k31 * (-13.287712379549449f / 32.0f));  // 10000^(-k31/32)
    float vw[8], cw[8], sw[8], aw[8];
#pragma unroll
    for (int w = 0; w < 8; ++w) {
        const int le = (wv << 3) + w;
        const int j = ejs[le];
        aw[w] = alphs[le];
        vw[w] = v[((size_t)(b * KK + j)) * DD + h * HD_ + lane];
        float ang = (float)(i - j) * invf;
        sincosf(ang, &sw[w], &cw[w]);
    }

#pragma unroll
    for (int t = 0; t < 2; ++t) {
        float upv = __shfl_xor(u_d, 32);
        float rotb = (lane < 32) ? -upv : upv;   // rotate_half
        float resid = 0.0f;
        float q[32];
#pragma unroll
        for (int wp = 0; wp < 4; ++wp) {
            float dlo = fmaf(u_d, cw[wp], rotb * sw[wp]) - vw[wp];
            float dhi = fmaf(u_d, cw[wp + 4], rotb * sw[wp + 4]) - vw[wp + 4];
            resid = fmaf(aw[wp], dlo, resid);
            resid = fmaf(aw[wp + 4], dhi, resid);
#pragma unroll
            for (int r = 0; r < 8; ++r) {
                float plo = lamr[wp][r] * dlo;
                float phi = lamr[wp + 4][r] * dhi;
                float recv = __shfl_xor(up32 ? plo : phi, 32);
                q[(wp << 3) + r] = (up32 ? phi : plo) + recv;
            }
        }
#pragma unroll
        for (int j = 0; j < 16; ++j) {
            float lo = q[j], hi = q[j + 16];
            float recv = __shfl_xor(up16 ? lo : hi, 16);
            q[j] = (up16 ? hi : lo) + recv;
        }
#pragma unroll
        for (int j = 0; j < 8; ++j) {
            float lo = q[j], hi = q[j + 8];
            float recv = __shfl_xor(up8 ? lo : hi, 8);
            q[j] = (up8 ? hi : lo) + recv;
        }
#pragma unroll
        for (int j = 0; j < 4; ++j) {
            float lo = q[j], hi = q[j + 4];
            float recv = __shfl_xor(up4 ? lo : hi, 4);
            q[j] = (up4 ? hi : lo) + recv;
        }
#pragma unroll
        for (int j = 0; j < 2; ++j) {
            float lo = q[j], hi = q[j + 2];
            float recv = __shfl_xor(up2 ? lo : hi, 2);
            q[j] = (up2 ? hi : lo) + recv;
        }
        {
            float lo = q[0], hi = q[1];
            float recv = __shfl_xor(up1 ? lo : hi, 1);
            q[0] = (up1 ? hi : lo) + recv;
        }
        // dt/ss for (w=lane>>3, r=lane&7) sits on lane; share via LDS
        dts[wv][lane] = q[0] * inv_ss;   // same-wave write->read, lgkmcnt-ordered
#pragma unroll
        for (int w = 0; w < 8; ++w) {
            float4 da = *(const float4*)&dts[wv][(w << 3)];
            float4 db = *(const float4*)&dts[wv][(w << 3) + 4];
            resid = fmaf(da.x, lamr[w][0], resid);
            resid = fmaf(da.y, lamr[w][1], resid);
            resid = fmaf(da.z, lamr[w][2], resid);
            resid = fmaf(da.w, lamr[w][3], resid);
            resid = fmaf(db.x, lamr[w][4], resid);
            resid = fmaf(db.y, lamr[w][5], resid);
            resid = fmaf(db.z, lamr[w][6], resid);
            resid = fmaf(db.w, lamr[w][7], resid);
        }
        u_d = fmaf((t == 0) ? -st0 : -st1, resid, u_d);
    }
    u[urow] = u_d;
}

// ---------------------------------------------------------------------------
extern "C" void kernel_launch(void* const* d_in, const int* in_sizes, int n_in,
                              void* d_out, int out_size, void* d_ws, size_t ws_size,
                              hipStream_t stream) {
    (void)in_sizes; (void)n_in; (void)out_size; (void)ws_size;
    const float* target     = (const float*)d_in[0];
    const float* context    = (const float*)d_in[1];
    const float* Wt         = (const float*)d_in[2];
    const float* bt         = (const float*)d_in[3];
    const float* Wc         = (const float*)d_in[4];
    const float* bc         = (const float*)d_in[5];
    const float* Ws1        = (const float*)d_in[6];
    const float* bs1        = (const float*)d_in[7];
    const float* Ws2        = (const float*)d_in[8];
    const float* bs2        = (const float*)d_in[9];
    const float* Wa1        = (const float*)d_in[10];
    const float* ba1        = (const float*)d_in[11];
    const float* Wa2        = (const float*)d_in[12];
    const float* ba2        = (const float*)d_in[13];
    const float* Wl1        = (const float*)d_in[14];
    const float* bl1        = (const float*)d_in[15];
    const float* Wl2        = (const float*)d_in[16];
    const float* bl2        = (const float*)d_in[17];
    const float* step_sizes = (const float*)d_in[18];
    const float* Wo         = (const float*)d_in[19];
    const float* bo         = (const float*)d_in[20];
    float* out = (float*)d_out;

    float* ws = (float*)d_ws;
    float* u    = ws;                    // 4096*512
    float* v    = ws + 2097152;
    float* t64  = ws + 4194304;          // 4096*64
    float* c64  = ws + 4456448;
    float* h16  = ws + 4718592;          // 32768*16
    float* alph = ws + 5242880;
    int*   ej   = (int*)(ws + 5275648);
    float* wct  = ws + 5308416;
    float* wcc  = ws + 5341184;

    prep_wcat<<<dim3((512 * 64 + 255) / 256), dim3(256), 0, stream>>>(Ws1, Wa1, Wl1, wct, wcc);

    gemm_bf16<<<dim3(32, 8), dim3(256), 0, stream>>>(target,  Wt, bt, u, 4096, 512, 512);
    gemm_bf16<<<dim3(32, 8), dim3(256), 0, stream>>>(context, Wc, bc, v, 4096, 512, 512);
    gemm_f32<<<dim3(64, 1), dim3(256), 0, stream>>>(target,  wct, nullptr, t64, 4096, 64, 512);
    gemm_f32<<<dim3(64, 1), dim3(256), 0, stream>>>(context, wcc, nullptr, c64, 4096, 64, 512);

    scores_topk<<<dim3(BB * LL), dim3(256), 0, stream>>>(t64, c64, bs1, Ws2, bs2, ej);

    edge_params<<<dim3(BB * NE / 256), dim3(256), 0, stream>>>(t64, c64, ej, bl1, ba1, Wa2, ba2, h16, alph);

    iterate_k<<<dim3(LL / 4, HH, BB), dim3(256), 0, stream>>>(u, v, ej, alph, h16, Wl2, bl2, step_sizes);

    gemm_bf16<<<dim3(32, 8), dim3(256), 0, stream>>>(u, Wo, bo, out, 4096, 512, 512);
}